// Round 2
// baseline (698.832 us; speedup 1.0000x reference)
//
#include <hip/hip_runtime.h>
#include <hip/hip_bf16.h>
#include <stdint.h>

// Problem shape (fixed by reference): M=8192 (8 shards x 1024), K=N=4096.
// C[m,n] = sum_k A[m,k] * W[n,k]  (weight stored [N,K], transed_weight==0)
#define K_DIM 4096
#define N_DIM 4096

typedef short short8 __attribute__((ext_vector_type(8)));      // 8 bf16 = 4 VGPRs (MFMA A/B frag)
typedef float f32x4 __attribute__((ext_vector_type(4)));       // MFMA C/D frag
typedef unsigned short ushort_t;
typedef unsigned short ushort8 __attribute__((ext_vector_type(8)));

// fp32 -> bf16 round-to-nearest-even
__device__ __forceinline__ ushort_t f2bf(float f) {
    uint32_t u = __float_as_uint(f);
    u += 0x7FFFu + ((u >> 16) & 1u);
    return (ushort_t)(u >> 16);
}

// Fused cast: first n8a chunks from `a`, next n8w chunks from `w`. 8 elems/thread.
__global__ void cast_to_bf16_2(const float* __restrict__ a, const float* __restrict__ w,
                               ushort_t* __restrict__ out_a, ushort_t* __restrict__ out_w,
                               int n8a, int n8w) {
    int i = blockIdx.x * blockDim.x + threadIdx.x;
    const float* in;
    ushort_t* out;
    int j;
    if (i < n8a) { in = a; out = out_a; j = i; }
    else if (i < n8a + n8w) { in = w; out = out_w; j = i - n8a; }
    else return;
    const float4* p = (const float4*)in + (size_t)j * 2;
    float4 v0 = p[0];
    float4 v1 = p[1];
    ushort8 r;
    r[0] = f2bf(v0.x); r[1] = f2bf(v0.y); r[2] = f2bf(v0.z); r[3] = f2bf(v0.w);
    r[4] = f2bf(v1.x); r[5] = f2bf(v1.y); r[6] = f2bf(v1.z); r[7] = f2bf(v1.w);
    *((ushort8*)out + j) = r;
}

// bf16 GEMM, B^T layout. 128x128 tile, BK=32, 256 threads (4 waves 2x2),
// each wave 64x64 as 4x4 MFMA 16x16x32 tiles.
// LDS layout: rows of 32 bf16 (64 B = 4 chunks of 16 B); chunk placement
// XOR-swizzled: row r, k-chunk q stored at slot q ^ ((r>>1)&3). This makes
// ds_read_b128 conflict-free (8-lane phase groups hit 8 distinct bank-groups)
// while keeping the global_load_lds wave-uniform+lane*16 constraint.
__global__ __launch_bounds__(256) void gemm_bf16_bt(
    const ushort_t* __restrict__ A,   // [M][K] bf16
    const ushort_t* __restrict__ B,   // [N][K] bf16
    float* __restrict__ C,            // [M][N] fp32
    int m_tiles)
{
    __shared__ ushort_t lds_a[128 * 32];   // 8 KB
    __shared__ ushort_t lds_b[128 * 32];

    // Grouped CTA swizzle: GROUP_M=8 M-tiles x full 32 N-tiles = 256 blocks/group
    // (one device wave) -> co-resident working set ~8 MB A + 32 MB B.
    const int num_pid_n = N_DIM / 128;            // 32
    const int group_rows = 8;
    const int pids_per_group = group_rows * num_pid_n;  // 256
    int pid = blockIdx.x;
    int group = pid / pids_per_group;
    int rem = pid - group * pids_per_group;
    int pid_m = group * group_rows + (rem & (group_rows - 1));
    int pid_n = rem >> 3;                          // rem / group_rows
    const int tile_m = pid_m * 128;
    const int tile_n = pid_n * 128;

    const int lane = threadIdx.x & 63;
    const int wave = threadIdx.x >> 6;
    const int wm = (wave >> 1) * 64;
    const int wn = (wave & 1) * 64;
    const int row16 = lane & 15;
    const int quad  = lane >> 4;
    const int ksw   = quad ^ ((row16 >> 1) & 3);   // read-side chunk slot (t/wave-invariant)

    f32x4 acc[4][4] = {};

    for (int k0 = 0; k0 < K_DIM; k0 += 32) {
        // Stage A/B tiles: 512 chunks of 16 B each. LDS position c holds
        // (row=c>>2, k-chunk=(c&3)^((row>>1)&3)).
        #pragma unroll
        for (int i = 0; i < 2; ++i) {
            int c    = wave * 128 + i * 64 + lane;
            int row  = c >> 2;
            int kch  = (c & 3) ^ ((row >> 1) & 3);
            const ushort_t* ga = A + (size_t)(tile_m + row) * K_DIM + k0 + kch * 8;
            const ushort_t* gb = B + (size_t)(tile_n + row) * K_DIM + k0 + kch * 8;
            int base = (wave * 128 + i * 64) * 8;  // wave-uniform, lane*16B auto
            __builtin_amdgcn_global_load_lds(
                (const __attribute__((address_space(1))) void*)ga,
                (__attribute__((address_space(3))) void*)(lds_a + base), 16, 0, 0);
            __builtin_amdgcn_global_load_lds(
                (const __attribute__((address_space(1))) void*)gb,
                (__attribute__((address_space(3))) void*)(lds_b + base), 16, 0, 0);
        }
        __syncthreads();

        // Fragment loads (ds_read_b128, conflict-free after swizzle):
        // A[m=lane&15][k=quad*8+j] -> row r = wm+t*16+row16, chunk q=quad at slot ksw.
        short8 a_frag[4], b_frag[4];
        #pragma unroll
        for (int t = 0; t < 4; ++t) {
            a_frag[t] = *(const short8*)(lds_a + (wm + t * 16 + row16) * 32 + ksw * 8);
            b_frag[t] = *(const short8*)(lds_b + (wn + t * 16 + row16) * 32 + ksw * 8);
        }
        #pragma unroll
        for (int mi = 0; mi < 4; ++mi)
            #pragma unroll
            for (int ni = 0; ni < 4; ++ni)
                acc[mi][ni] = __builtin_amdgcn_mfma_f32_16x16x32_bf16(
                    a_frag[mi], b_frag[ni], acc[mi][ni], 0, 0, 0);

        __syncthreads();
    }

    // Epilogue: C/D layout col=lane&15, row=quad*4+reg
    #pragma unroll
    for (int mi = 0; mi < 4; ++mi) {
        #pragma unroll
        for (int r = 0; r < 4; ++r) {
            int m = tile_m + wm + mi * 16 + quad * 4 + r;
            float* crow = C + (size_t)m * N_DIM + tile_n + wn;
            #pragma unroll
            for (int ni = 0; ni < 4; ++ni)
                crow[ni * 16 + row16] = acc[mi][ni][r];
        }
    }
}

// Safety-net fallback (ws too small; not expected).
__global__ void gemm_naive_f32(const float* __restrict__ A, const float* __restrict__ W,
                               float* __restrict__ C, int m_tot) {
    int n = blockIdx.x * blockDim.x + threadIdx.x;
    int m = blockIdx.y;
    if (n >= N_DIM || m >= m_tot) return;
    const float* a = A + (size_t)m * K_DIM;
    const float* w = W + (size_t)n * K_DIM;
    float s = 0.f;
    for (int k = 0; k < K_DIM; ++k) s += a[k] * w[k];
    C[(size_t)m * N_DIM + n] = s;
}

extern "C" void kernel_launch(void* const* d_in, const int* in_sizes, int n_in,
                              void* d_out, int out_size, void* d_ws, size_t ws_size,
                              hipStream_t stream) {
    const float* a_f32 = (const float*)d_in[0];   // [8192,4096]
    const float* w_f32 = (const float*)d_in[1];   // [4096,4096] ([N,K])
    float* out = (float*)d_out;

    const size_t a_elems = (size_t)in_sizes[0];
    const size_t w_elems = (size_t)in_sizes[1];
    const int m_tot = (int)(a_elems / K_DIM);     // 8192

    const size_t need = (a_elems + w_elems) * sizeof(ushort_t);
    if (ws_size >= need) {
        ushort_t* a_bf = (ushort_t*)d_ws;
        ushort_t* w_bf = a_bf + a_elems;

        int n8a = (int)(a_elems / 8);
        int n8w = (int)(w_elems / 8);
        int n8 = n8a + n8w;
        cast_to_bf16_2<<<(n8 + 255) / 256, 256, 0, stream>>>(a_f32, w_f32, a_bf, w_bf, n8a, n8w);

        int m_tiles = m_tot / 128;                // 64
        int nblocks = (N_DIM / 128) * m_tiles;    // 2048
        gemm_bf16_bt<<<nblocks, 256, 0, stream>>>(a_bf, w_bf, out, m_tiles);
    } else {
        dim3 grid(N_DIM / 256, m_tot);
        gemm_naive_f32<<<grid, 256, 0, stream>>>(a_f32, w_f32, out, m_tot);
    }
}

// Round 3
// 538.878 us; speedup vs baseline: 1.2968x; 1.2968x over previous
//
#include <hip/hip_runtime.h>
#include <hip/hip_bf16.h>
#include <stdint.h>

// Problem shape (fixed by reference): M=8192 (8 shards x 1024), K=N=4096.
// C[m,n] = sum_k A[m,k] * W[n,k]  (weight stored [N,K], transed_weight==0)
#define K_DIM 4096
#define N_DIM 4096
#define BM 256
#define BN 128

typedef short short8 __attribute__((ext_vector_type(8)));      // 8 bf16 = 4 VGPRs (MFMA A/B frag)
typedef float f32x4 __attribute__((ext_vector_type(4)));       // MFMA C/D frag
typedef unsigned short ushort_t;
typedef unsigned short ushort8 __attribute__((ext_vector_type(8)));

// fp32 -> bf16 round-to-nearest-even
__device__ __forceinline__ ushort_t f2bf(float f) {
    uint32_t u = __float_as_uint(f);
    u += 0x7FFFu + ((u >> 16) & 1u);
    return (ushort_t)(u >> 16);
}

// Fused cast: first n8a chunks from `a`, next n8w chunks from `w`. 8 elems/thread.
__global__ void cast_to_bf16_2(const float* __restrict__ a, const float* __restrict__ w,
                               ushort_t* __restrict__ out_a, ushort_t* __restrict__ out_w,
                               int n8a, int n8w) {
    int i = blockIdx.x * blockDim.x + threadIdx.x;
    const float* in;
    ushort_t* out;
    int j;
    if (i < n8a) { in = a; out = out_a; j = i; }
    else if (i < n8a + n8w) { in = w; out = out_w; j = i - n8a; }
    else return;
    const float4* p = (const float4*)in + (size_t)j * 2;
    float4 v0 = p[0];
    float4 v1 = p[1];
    ushort8 r;
    r[0] = f2bf(v0.x); r[1] = f2bf(v0.y); r[2] = f2bf(v0.z); r[3] = f2bf(v0.w);
    r[4] = f2bf(v1.x); r[5] = f2bf(v1.y); r[6] = f2bf(v1.z); r[7] = f2bf(v1.w);
    *((ushort8*)out + j) = r;
}

// bf16 GEMM, B^T layout. 256x128 tile, BK=32, 512 threads (8 waves, 4m x 2n),
// each wave 64x64 as 4x4 MFMA 16x16x32 tiles.
// LDS rows of 32 bf16 (64 B = 4 chunks of 16 B); chunk placement XOR-swizzled:
// row r, k-chunk q stored at slot q ^ ((r>>1)&3) -> ds_read_b128 conflict-free
// (verified round 2: SQ_LDS_BANK_CONFLICT == 0) while honoring the
// global_load_lds wave-uniform-base + lane*16 constraint.
__global__ __launch_bounds__(512) void gemm_bf16_bt(
    const ushort_t* __restrict__ A,   // [M][K] bf16
    const ushort_t* __restrict__ B,   // [N][K] bf16
    float* __restrict__ C)            // [M][N] fp32
{
    __shared__ ushort_t lds_a[BM * 32];   // 16 KB
    __shared__ ushort_t lds_b[BN * 32];   // 8 KB

    // Natural n-fastest order (round-1 best L2 behavior): each XCD sees 4
    // N-tile columns via the i%8 round-robin; L3 (256 MB) covers cross-XCD A reuse.
    const int pid   = blockIdx.x;
    const int pid_n = pid & (N_DIM / BN - 1);    // % 32
    const int pid_m = pid >> 5;                  // / 32
    const int tile_m = pid_m * BM;
    const int tile_n = pid_n * BN;

    const int lane = threadIdx.x & 63;
    const int wave = threadIdx.x >> 6;           // 0..7
    const int wm = (wave >> 1) * 64;             // 4 wave-rows
    const int wn = (wave & 1) * 64;              // 2 wave-cols
    const int row16 = lane & 15;
    const int quad  = lane >> 4;
    const int ksw   = quad ^ ((row16 >> 1) & 3); // read-side chunk slot

    f32x4 acc[4][4] = {};

    // Staging: A-tile = 1024 16B-chunks, B-tile = 512 chunks; 1536 total =
    // 8 waves x 3 iters x 64 lanes. Chunk c: row=c>>2, slot c&3 holds
    // k-chunk (c&3)^((row>>1)&3). Matrix choice is wave-uniform (1024 % 64 == 0).
    for (int k0 = 0; k0 < K_DIM; k0 += 32) {
        #pragma unroll
        for (int i = 0; i < 3; ++i) {
            int cbase = wave * 192 + i * 64;     // wave-uniform
            int c     = cbase + lane;
            if (cbase < 1024) {                  // A chunk
                int row = c >> 2;
                int kch = (c & 3) ^ ((row >> 1) & 3);
                const ushort_t* ga = A + (size_t)(tile_m + row) * K_DIM + k0 + kch * 8;
                __builtin_amdgcn_global_load_lds(
                    (const __attribute__((address_space(1))) void*)ga,
                    (__attribute__((address_space(3))) void*)(lds_a + cbase * 8), 16, 0, 0);
            } else {                             // B chunk
                int cb  = c - 1024;
                int row = cb >> 2;
                int kch = (cb & 3) ^ ((row >> 1) & 3);
                const ushort_t* gb = B + (size_t)(tile_n + row) * K_DIM + k0 + kch * 8;
                __builtin_amdgcn_global_load_lds(
                    (const __attribute__((address_space(1))) void*)gb,
                    (__attribute__((address_space(3))) void*)(lds_b + (cbase - 1024) * 8), 16, 0, 0);
            }
        }
        __syncthreads();

        // Fragment loads (ds_read_b128, conflict-free):
        short8 a_frag[4], b_frag[4];
        #pragma unroll
        for (int t = 0; t < 4; ++t) {
            a_frag[t] = *(const short8*)(lds_a + (wm + t * 16 + row16) * 32 + ksw * 8);
            b_frag[t] = *(const short8*)(lds_b + (wn + t * 16 + row16) * 32 + ksw * 8);
        }
        #pragma unroll
        for (int mi = 0; mi < 4; ++mi)
            #pragma unroll
            for (int ni = 0; ni < 4; ++ni)
                acc[mi][ni] = __builtin_amdgcn_mfma_f32_16x16x32_bf16(
                    a_frag[mi], b_frag[ni], acc[mi][ni], 0, 0, 0);

        __syncthreads();
    }

    // Epilogue: C/D layout col=lane&15, row=quad*4+reg
    #pragma unroll
    for (int mi = 0; mi < 4; ++mi) {
        #pragma unroll
        for (int r = 0; r < 4; ++r) {
            int m = tile_m + wm + mi * 16 + quad * 4 + r;
            float* crow = C + (size_t)m * N_DIM + tile_n + wn;
            #pragma unroll
            for (int ni = 0; ni < 4; ++ni)
                crow[ni * 16 + row16] = acc[mi][ni][r];
        }
    }
}

// Safety-net fallback (ws too small; not expected).
__global__ void gemm_naive_f32(const float* __restrict__ A, const float* __restrict__ W,
                               float* __restrict__ C, int m_tot) {
    int n = blockIdx.x * blockDim.x + threadIdx.x;
    int m = blockIdx.y;
    if (n >= N_DIM || m >= m_tot) return;
    const float* a = A + (size_t)m * K_DIM;
    const float* w = W + (size_t)n * K_DIM;
    float s = 0.f;
    for (int k = 0; k < K_DIM; ++k) s += a[k] * w[k];
    C[(size_t)m * N_DIM + n] = s;
}

extern "C" void kernel_launch(void* const* d_in, const int* in_sizes, int n_in,
                              void* d_out, int out_size, void* d_ws, size_t ws_size,
                              hipStream_t stream) {
    const float* a_f32 = (const float*)d_in[0];   // [8192,4096]
    const float* w_f32 = (const float*)d_in[1];   // [4096,4096] ([N,K])
    float* out = (float*)d_out;

    const size_t a_elems = (size_t)in_sizes[0];
    const size_t w_elems = (size_t)in_sizes[1];
    const int m_tot = (int)(a_elems / K_DIM);     // 8192

    const size_t need = (a_elems + w_elems) * sizeof(ushort_t);
    if (ws_size >= need && (m_tot % BM) == 0) {
        ushort_t* a_bf = (ushort_t*)d_ws;
        ushort_t* w_bf = a_bf + a_elems;

        int n8a = (int)(a_elems / 8);
        int n8w = (int)(w_elems / 8);
        int n8 = n8a + n8w;
        cast_to_bf16_2<<<(n8 + 255) / 256, 256, 0, stream>>>(a_f32, w_f32, a_bf, w_bf, n8a, n8w);

        int nblocks = (N_DIM / BN) * (m_tot / BM);   // 32 x 32 = 1024
        gemm_bf16_bt<<<nblocks, 512, 0, stream>>>(a_bf, w_bf, out);
    } else {
        dim3 grid(N_DIM / 256, m_tot);
        gemm_naive_f32<<<grid, 256, 0, stream>>>(a_f32, w_f32, out, m_tot);
    }
}